// Round 4
// baseline (217.947 us; speedup 1.0000x reference)
//
#include <hip/hip_runtime.h>
#include <hip/hip_bf16.h>

#define VOCAB 100000
#define DIM   128
#define BATCH 16384
#define KNEG  20
#define NNEG  (BATCH * KNEG)     // 327680
#define CAP   16                 // slots per vocab row (Poisson lambda=3.28; P(>16) ~ 1e-7)
#define OVF_CAP 65536

// d_ws layout (bytes)
#define CNT_OFF   0ul            // u32[VOCAB]          400,000
#define OVFC_OFF  400000ul       // u32[1]
#define SLOT_OFF  400064ul       // u16[VOCAB*CAP]    3,200,000
#define TBF_OFF   3600128ul      // u16[BATCH*DIM]    4,194,304  (bf16 t-vectors)
#define OVF_OFF   7794432ul      // u32[OVF_CAP]        262,144
#define WS_NEED   (OVF_OFF + OVF_CAP * 4ul)   // 8,056,576

typedef float v4f __attribute__((ext_vector_type(4)));

__device__ __forceinline__ unsigned short f2bf(float f) {
    unsigned u = __float_as_uint(f);
    return (unsigned short)((u + 0x7fffu + ((u >> 16) & 1u)) >> 16);  // RN-even
}
__device__ __forceinline__ float bf2f(unsigned short u) {
    return __uint_as_float(((unsigned)u) << 16);
}
__device__ __forceinline__ float log_sigmoid(float x) {
    return fminf(x, 0.0f) - __logf(1.0f + __expf(-fabsf(x)));
}

// ---------------- Kernel 1: scatter negatives by row + positive pass + t->bf16 ----
// Blocks [0,1280):   scatter 327680 neg entries into per-row slot buckets.
// Blocks [1280,3328): half-wave per batch item: pos score + store t_bf16.
__global__ __launch_bounds__(256) void scatter_pos_kernel(
    const int*   __restrict__ target,
    const int*   __restrict__ context,
    const int*   __restrict__ neg_samples,
    const float* __restrict__ in_embed,
    const float* __restrict__ out_embed,
    unsigned*       cnt, unsigned* ovfc,
    unsigned short* slots, unsigned short* tbf, unsigned* ovf,
    float* __restrict__ out)
{
    if (blockIdx.x < 1280) {                       // 1280*256 == NNEG exactly
        const int i = blockIdx.x * 256 + threadIdx.x;
        const int b = i / KNEG;
        const int r = neg_samples[i];
        const unsigned pos = atomicAdd(&cnt[r], 1u);
        if (pos < CAP) {
            slots[r * CAP + pos] = (unsigned short)b;
        } else {
            const unsigned o = atomicAdd(ovfc, 1u);
            if (o < OVF_CAP) ovf[o] = ((unsigned)r << 14) | (unsigned)b;
        }
        return;
    }
    // Positive-pair + conversion part: half-wave (32 lanes) per batch item.
    const int blk  = blockIdx.x - 1280;            // 0..2047
    const int lane = threadIdx.x & 63;
    const int half = lane >> 5;
    const int sub  = lane & 31;
    const int wave = threadIdx.x >> 6;
    const int b    = blk * 8 + wave * 2 + half;    // 0..16383, exactly once

    const int trow = target[b];
    const int crow = context[b];
    const float4 t4 = *(const float4*)(in_embed  + (size_t)trow * DIM + sub * 4);
    const float4 c4 = *(const float4*)(out_embed + (size_t)crow * DIM + sub * 4);

    // store t as bf16 (256 B contiguous per row)
    ushort4 u;
    u.x = f2bf(t4.x); u.y = f2bf(t4.y); u.z = f2bf(t4.z); u.w = f2bf(t4.w);
    *(ushort4*)(tbf + (size_t)b * DIM + sub * 4) = u;

    float v = t4.x * c4.x + t4.y * c4.y + t4.z * c4.z + t4.w * c4.w;
    #pragma unroll
    for (int m = 1; m < 32; m <<= 1) v += __shfl_xor(v, m, 64);  // within half
    const float ls = log_sigmoid(v);               // uniform across the half

    __shared__ float smem[8];
    if (sub == 0) smem[wave * 2 + half] = ls;
    __syncthreads();
    if (threadIdx.x == 0) {
        float tot = 0.0f;
        #pragma unroll
        for (int j = 0; j < 8; ++j) tot += smem[j];
        atomicAdd(out, -tot * (1.0f / (float)BATCH));
    }
}

// ---------------- Kernel 2: stream vocab rows, gather L2-resident bf16 t ---------
// Half-wave per vocab row, rows in sequential order -> out_embed is streamed
// (nontemporal: don't evict the 4 MB t_bf16 table from L2).
__global__ __launch_bounds__(256) void neg_rows_kernel(
    const float* __restrict__ out_embed,
    const unsigned* __restrict__ cnt, const unsigned* __restrict__ ovfc,
    const unsigned short* __restrict__ slots,
    const unsigned short* __restrict__ tbf,
    const unsigned* __restrict__ ovf,
    float* __restrict__ out)
{
    const int lane  = threadIdx.x & 63;
    const int half  = lane >> 5;
    const int sub   = lane & 31;
    const int wave  = threadIdx.x >> 6;
    const int ghalf = (blockIdx.x * 4 + wave) * 2 + half;   // 0..16383
    const int nhalf = gridDim.x * 8;                        // 16384

    float acc = 0.0f;

    for (int r = ghalf; r < VOCAB; r += nhalf) {
        const unsigned c = __builtin_nontemporal_load(&cnt[r]);
        if (c == 0) continue;

        const v4f o4 = __builtin_nontemporal_load(
            (const v4f*)(out_embed + (size_t)r * DIM + sub * 4));

        const int m = (c < CAP) ? (int)c : CAP;
        for (int j = 0; j < m; ++j) {
            const int b = __builtin_nontemporal_load(&slots[r * CAP + j]);
            const uint2 tu = *(const uint2*)(tbf + (size_t)b * DIM + sub * 4);
            float p = o4.x * bf2f((unsigned short)(tu.x & 0xffff))
                    + o4.y * bf2f((unsigned short)(tu.x >> 16))
                    + o4.z * bf2f((unsigned short)(tu.y & 0xffff))
                    + o4.w * bf2f((unsigned short)(tu.y >> 16));
            #pragma unroll
            for (int s = 1; s < 32; s <<= 1) p += __shfl_xor(p, s, 64);
            acc += log_sigmoid(-p);
        }
    }

    // Overflow entries (expected ~0, handled for correctness).
    unsigned novf = *ovfc;
    if (novf > OVF_CAP) novf = OVF_CAP;
    for (unsigned i = ghalf; i < novf; i += nhalf) {
        const unsigned e = ovf[i];
        const int r = (int)(e >> 14);
        const int b = (int)(e & 16383u);
        const float4 o4 = *(const float4*)(out_embed + (size_t)r * DIM + sub * 4);
        const uint2 tu = *(const uint2*)(tbf + (size_t)b * DIM + sub * 4);
        float p = o4.x * bf2f((unsigned short)(tu.x & 0xffff))
                + o4.y * bf2f((unsigned short)(tu.x >> 16))
                + o4.z * bf2f((unsigned short)(tu.y & 0xffff))
                + o4.w * bf2f((unsigned short)(tu.y >> 16));
        #pragma unroll
        for (int s = 1; s < 32; s <<= 1) p += __shfl_xor(p, s, 64);
        acc += log_sigmoid(-p);
    }

    __shared__ float smem[8];
    if (sub == 0) smem[wave * 2 + half] = acc;   // acc uniform within half
    __syncthreads();
    if (threadIdx.x == 0) {
        float tot = 0.0f;
        #pragma unroll
        for (int j = 0; j < 8; ++j) tot += smem[j];
        atomicAdd(out, -tot * (1.0f / (float)BATCH));
    }
}

// ---------------- Fallback (R2 structure) if ws is too small --------------------
__global__ __launch_bounds__(256) void skipgram_loss_kernel(
    const int* __restrict__ target, const int* __restrict__ context,
    const int* __restrict__ neg_samples,
    const float* __restrict__ in_embed, const float* __restrict__ out_embed,
    float* __restrict__ out)
{
    const int lane = threadIdx.x & 63, half = lane >> 5, sub = lane & 31;
    const int wave = threadIdx.x >> 6, wpb = blockDim.x >> 6;
    const int gwave = blockIdx.x * wpb + wave, nwav = gridDim.x * wpb;
    float acc = 0.0f;
    for (int b0 = gwave * 2; b0 < BATCH; b0 += nwav * 2) {
        const int b = b0 + half;
        const float4 t4 = *(const float4*)(in_embed  + (size_t)target[b]  * DIM + sub * 4);
        const float4 c4 = *(const float4*)(out_embed + (size_t)context[b] * DIM + sub * 4);
        const int myidx = (sub < KNEG) ? neg_samples[b * KNEG + sub] : 0;
        int nrow[KNEG];
        #pragma unroll
        for (int k = 0; k < KNEG; ++k) nrow[k] = __shfl(myidx, k, 32);
        float p[KNEG + 1];
        p[0] = t4.x * c4.x + t4.y * c4.y + t4.z * c4.z + t4.w * c4.w;
        #pragma unroll
        for (int k = 0; k < KNEG; ++k) {
            const float4 n4 = *(const float4*)(out_embed + (size_t)nrow[k] * DIM + sub * 4);
            p[k + 1] = t4.x * n4.x + t4.y * n4.y + t4.z * n4.z + t4.w * n4.w;
        }
        #pragma unroll
        for (int k = 0; k < KNEG + 1; ++k) {
            float v = p[k];
            #pragma unroll
            for (int m = 1; m < 32; m <<= 1) v += __shfl_xor(v, m, 64);
            const float x = (k == 0) ? v : -v;
            acc += log_sigmoid(x);
        }
    }
    __shared__ float smem[8];
    if (sub == 0) smem[wave * 2 + half] = acc;
    __syncthreads();
    if (threadIdx.x == 0) {
        float tot = 0.0f;
        for (int i = 0; i < 8; ++i) tot += smem[i];
        atomicAdd(out, -tot * (1.0f / (float)BATCH));
    }
}

extern "C" void kernel_launch(void* const* d_in, const int* in_sizes, int n_in,
                              void* d_out, int out_size, void* d_ws, size_t ws_size,
                              hipStream_t stream) {
    const int*   target      = (const int*)  d_in[0];
    const int*   context     = (const int*)  d_in[1];
    const int*   neg_samples = (const int*)  d_in[2];
    const float* in_embed    = (const float*)d_in[3];
    const float* out_embed   = (const float*)d_in[4];
    float*       out         = (float*)d_out;

    hipMemsetAsync(out, 0, sizeof(float), stream);

    if (ws_size < WS_NEED) {   // fallback: ws too small for the inverted pipeline
        skipgram_loss_kernel<<<2048, 256, 0, stream>>>(
            target, context, neg_samples, in_embed, out_embed, out);
        return;
    }

    char* ws = (char*)d_ws;
    unsigned*       cnt   = (unsigned*)      (ws + CNT_OFF);
    unsigned*       ovfc  = (unsigned*)      (ws + OVFC_OFF);
    unsigned short* slots = (unsigned short*)(ws + SLOT_OFF);
    unsigned short* tbf   = (unsigned short*)(ws + TBF_OFF);
    unsigned*       ovf   = (unsigned*)      (ws + OVF_OFF);

    // zero cnt + ovf_cnt (contiguous)
    hipMemsetAsync(ws, 0, OVFC_OFF + 4, stream);

    scatter_pos_kernel<<<3328, 256, 0, stream>>>(
        target, context, neg_samples, in_embed, out_embed,
        cnt, ovfc, slots, tbf, ovf, out);

    neg_rows_kernel<<<2048, 256, 0, stream>>>(
        out_embed, cnt, ovfc, slots, tbf, ovf, out);
}

// Round 6
// 177.133 us; speedup vs baseline: 1.2304x; 1.2304x over previous
//
#include <hip/hip_runtime.h>
#include <hip/hip_bf16.h>

#define VOCAB 100000
#define DIM   128
#define BATCH 16384
#define KNEG  20

// ws layout: fp8 copy of out_embed, then fp8 gathered t-rows.
#define TF8_OFF 12800000ul                       // VOCAB*DIM bytes
#define WS_NEED (TF8_OFF + (size_t)BATCH * DIM)  // 14,897,152

#define CONV_BLOCKS 1024

typedef float v2f __attribute__((ext_vector_type(2)));
typedef float v4f __attribute__((ext_vector_type(4)));

#if __has_builtin(__builtin_amdgcn_cvt_pk_f32_fp8) && __has_builtin(__builtin_amdgcn_cvt_pk_fp8_f32)
#define HW_FP8 1
#endif

__device__ __forceinline__ float log_sigmoid(float x) {
    return fminf(x, 0.0f) - __logf(1.0f + __expf(-fabsf(x)));
}

#ifndef HW_FP8
// Manual OCP e4m3fn encode, RN-even (only used if HW cvt builtins absent).
__device__ __forceinline__ unsigned f2fp8(float f) {
    unsigned u = __float_as_uint(f);
    unsigned s = (u >> 24) & 0x80u;
    float a = fabsf(f);
    if (!(a >= 0x1p-10f)) return s;                       // rounds to +-0
    if (a >= 448.0f) return s | 0x7Eu;                    // satfinite
    int E = (int)((u >> 23) & 0xffu) - 127;
    if (E < -6) E = -6;
    float step  = __uint_as_float((unsigned)(E - 3 + 127) << 23);  // 2^(E-3)
    float rstep = __uint_as_float((unsigned)(3 - E + 127) << 23);  // 2^(3-E)
    float r = rintf(a * rstep) * step;                    // nearest e4m3 value
    unsigned ub = __float_as_uint(r);
    unsigned code;
    if (r < 0x1p-6f) code = (unsigned)(r * 512.0f);       // subnormal: man = r*2^9
    else code = ((((ub >> 23) & 0xffu) - 120u) << 3) | ((ub >> 20) & 7u);
    return s | code;
}
#endif

__device__ __forceinline__ unsigned enc4(float a, float b, float c, float d) {
#ifdef HW_FP8
    int w = __builtin_amdgcn_cvt_pk_fp8_f32(a, b, 0, false);
    w = __builtin_amdgcn_cvt_pk_fp8_f32(c, d, w, true);
    return (unsigned)w;
#else
    return f2fp8(a) | (f2fp8(b) << 8) | (f2fp8(c) << 16) | (f2fp8(d) << 24);
#endif
}

// HI must be a compile-time constant: the builtin's word selector is an ICE.
template <bool HI>
__device__ __forceinline__ v2f dec2(unsigned w) {
#ifdef HW_FP8
    return __builtin_amdgcn_cvt_pk_f32_fp8((int)w, HI);
#else
    // e4m3fn -> f32: place sign+7 payload bits into f32 fields, scale by 2^120.
    unsigned v0 = (w >> (HI ? 16 : 0)) & 0xffu;
    unsigned v1 = (w >> (HI ? 24 : 8)) & 0xffu;
    v2f r;
    r.x = __uint_as_float(((v0 & 0x80u) << 24) | ((v0 & 0x7fu) << 20)) * 0x1p120f;
    r.y = __uint_as_float(((v1 & 0x80u) << 24) | ((v1 & 0x7fu) << 20)) * 0x1p120f;
    return r;
#endif
}

// ---- Dispatch 1: fp8 table conversion (role A) + positive pass + t->fp8 (role B)
__global__ __launch_bounds__(256) void convert_pos_kernel(
    const int*   __restrict__ target,
    const int*   __restrict__ context,
    const float* __restrict__ in_embed,
    const float* __restrict__ out_embed,
    unsigned char* __restrict__ nf8,
    unsigned char* __restrict__ tf8,
    float* __restrict__ out)
{
    if (blockIdx.x < CONV_BLOCKS) {
        // Stream out_embed (51.2 MB) -> fp8 (12.8 MB). Nontemporal reads:
        // don't thrash L2 (the fp8 writes should stay resident-ish).
        const int n4   = VOCAB * DIM / 4;          // 3,200,000 float4
        const int tid  = blockIdx.x * 256 + threadIdx.x;
        const int step = CONV_BLOCKS * 256;
        unsigned* dst = (unsigned*)nf8;
        for (int i = tid; i < n4; i += step) {
            const v4f v = __builtin_nontemporal_load((const v4f*)out_embed + i);
            dst[i] = enc4(v.x, v.y, v.z, v.w);
        }
        return;
    }
    // Role B: half-wave per batch item, pos score (f32, exact) + t fp8 store.
    const int blk  = blockIdx.x - CONV_BLOCKS;     // 0..2047
    const int lane = threadIdx.x & 63;
    const int half = lane >> 5;
    const int sub  = lane & 31;
    const int wave = threadIdx.x >> 6;
    const int b    = blk * 8 + wave * 2 + half;    // each b exactly once

    const int trow = target[b];
    const int crow = context[b];
    const v4f t4 = *(const v4f*)(in_embed  + (size_t)trow * DIM + sub * 4);
    const v4f c4 = *(const v4f*)(out_embed + (size_t)crow * DIM + sub * 4);

    *(unsigned*)(tf8 + (size_t)b * DIM + sub * 4) = enc4(t4.x, t4.y, t4.z, t4.w);

    float v = t4.x * c4.x + t4.y * c4.y + t4.z * c4.z + t4.w * c4.w;
    #pragma unroll
    for (int m = 1; m < 32; m <<= 1) v += __shfl_xor(v, m, 64);  // within half
    const float ls = log_sigmoid(v);

    __shared__ float smem[8];
    if (sub == 0) smem[wave * 2 + half] = ls;
    __syncthreads();
    if (threadIdx.x == 0) {
        float tot = 0.0f;
        #pragma unroll
        for (int j = 0; j < 8; ++j) tot += smem[j];
        atomicAdd(out, -tot * (1.0f / (float)BATCH));
    }
}

// ---- Dispatch 2: R2-parallel neg gather from fp8 tables -----------------------
// Half-wave per batch row; each neg row = 128 B (one dword/lane), 20 loads in
// flight. Quad transpose-reduce: lane ends owning entry 4q+(lane&3), so one
// log_sigmoid covers 4 entries and shuffle count drops ~2.5x.
__global__ __launch_bounds__(256) void neg_fp8_kernel(
    const int* __restrict__ neg_samples,
    const unsigned char* __restrict__ nf8,
    const unsigned char* __restrict__ tf8,
    float* __restrict__ out)
{
    const int lane = threadIdx.x & 63;
    const int half = lane >> 5;
    const int sub  = lane & 31;
    const int wave = threadIdx.x >> 6;
    const int b    = (blockIdx.x * 4 + wave) * 2 + half;   // 0..16383

    const unsigned tw = *(const unsigned*)(tf8 + (size_t)b * DIM + sub * 4);
    const v2f t01 = dec2<false>(tw);
    const v2f t23 = dec2<true>(tw);

    const int myidx = (sub < KNEG) ? neg_samples[b * KNEG + sub] : 0;

    unsigned nw[KNEG];
    #pragma unroll
    for (int k = 0; k < KNEG; ++k) {
        const int r = __shfl(myidx, k, 32);
        nw[k] = *(const unsigned*)(nf8 + (size_t)r * DIM + sub * 4);
    }

    float p[KNEG];
    #pragma unroll
    for (int k = 0; k < KNEG; ++k) {
        const v2f a = dec2<false>(nw[k]);
        const v2f c = dec2<true>(nw[k]);
        p[k] = t01.x * a.x + t01.y * a.y + t23.x * c.x + t23.y * c.y;
    }

    const bool s1 = (lane & 1) != 0;
    const bool s2 = (lane & 2) != 0;
    float acc = 0.0f;
    #pragma unroll
    for (int q = 0; q < KNEG / 4; ++q) {
        const float p0 = p[4*q], p1 = p[4*q+1], p2 = p[4*q+2], p3 = p[4*q+3];
        float m0 = s1 ? p1 : p0, y0 = s1 ? p0 : p1;
        float m1 = s1 ? p3 : p2, y1 = s1 ? p2 : p3;
        m0 += __shfl_xor(y0, 1, 64);
        m1 += __shfl_xor(y1, 1, 64);
        float m = s2 ? m1 : m0, y = s2 ? m0 : m1;
        m += __shfl_xor(y, 2, 64);
        m += __shfl_xor(m, 4, 64);
        m += __shfl_xor(m, 8, 64);
        m += __shfl_xor(m, 16, 64);
        // m = score of entry 4q+(lane&3), summed over the 32-lane half.
        acc += log_sigmoid(-m);
    }
    // Sum the 4 lane-classes -> uniform total of all 20 entries.
    acc += __shfl_xor(acc, 1, 64);
    acc += __shfl_xor(acc, 2, 64);

    __shared__ float smem[8];
    if (sub == 0) smem[wave * 2 + half] = acc;
    __syncthreads();
    if (threadIdx.x == 0) {
        float tot = 0.0f;
        #pragma unroll
        for (int j = 0; j < 8; ++j) tot += smem[j];
        atomicAdd(out, -tot * (1.0f / (float)BATCH));
    }
}

// ---- Fallback (R2, proven) if ws too small ------------------------------------
__global__ __launch_bounds__(256) void skipgram_loss_kernel(
    const int* __restrict__ target, const int* __restrict__ context,
    const int* __restrict__ neg_samples,
    const float* __restrict__ in_embed, const float* __restrict__ out_embed,
    float* __restrict__ out)
{
    const int lane = threadIdx.x & 63, half = lane >> 5, sub = lane & 31;
    const int wave = threadIdx.x >> 6, wpb = blockDim.x >> 6;
    const int gwave = blockIdx.x * wpb + wave, nwav = gridDim.x * wpb;
    float acc = 0.0f;
    for (int b0 = gwave * 2; b0 < BATCH; b0 += nwav * 2) {
        const int b = b0 + half;
        const float4 t4 = *(const float4*)(in_embed  + (size_t)target[b]  * DIM + sub * 4);
        const float4 c4 = *(const float4*)(out_embed + (size_t)context[b] * DIM + sub * 4);
        const int myidx = (sub < KNEG) ? neg_samples[b * KNEG + sub] : 0;
        int nrow[KNEG];
        #pragma unroll
        for (int k = 0; k < KNEG; ++k) nrow[k] = __shfl(myidx, k, 32);
        float p[KNEG + 1];
        p[0] = t4.x * c4.x + t4.y * c4.y + t4.z * c4.z + t4.w * c4.w;
        #pragma unroll
        for (int k = 0; k < KNEG; ++k) {
            const float4 n4 = *(const float4*)(out_embed + (size_t)nrow[k] * DIM + sub * 4);
            p[k + 1] = t4.x * n4.x + t4.y * n4.y + t4.z * n4.z + t4.w * n4.w;
        }
        #pragma unroll
        for (int k = 0; k < KNEG + 1; ++k) {
            float v = p[k];
            #pragma unroll
            for (int m = 1; m < 32; m <<= 1) v += __shfl_xor(v, m, 64);
            acc += log_sigmoid((k == 0) ? v : -v);
        }
    }
    __shared__ float smem[8];
    if (sub == 0) smem[wave * 2 + half] = acc;
    __syncthreads();
    if (threadIdx.x == 0) {
        float tot = 0.0f;
        for (int i = 0; i < 8; ++i) tot += smem[i];
        atomicAdd(out, -tot * (1.0f / (float)BATCH));
    }
}

extern "C" void kernel_launch(void* const* d_in, const int* in_sizes, int n_in,
                              void* d_out, int out_size, void* d_ws, size_t ws_size,
                              hipStream_t stream) {
    const int*   target      = (const int*)  d_in[0];
    const int*   context     = (const int*)  d_in[1];
    const int*   neg_samples = (const int*)  d_in[2];
    const float* in_embed    = (const float*)d_in[3];
    const float* out_embed   = (const float*)d_in[4];
    float*       out         = (float*)d_out;

    (void)hipMemsetAsync(out, 0, sizeof(float), stream);

    if (ws_size < WS_NEED) {
        skipgram_loss_kernel<<<2048, 256, 0, stream>>>(
            target, context, neg_samples, in_embed, out_embed, out);
        return;
    }

    unsigned char* nf8 = (unsigned char*)d_ws;
    unsigned char* tf8 = nf8 + TF8_OFF;

    convert_pos_kernel<<<CONV_BLOCKS + 2048, 256, 0, stream>>>(
        target, context, in_embed, out_embed, nf8, tf8, out);

    neg_fp8_kernel<<<2048, 256, 0, stream>>>(neg_samples, nf8, tf8, out);
}